// Round 18
// baseline (328.049 us; speedup 1.0000x reference)
//
#include <hip/hip_runtime.h>
#include <math.h>

#define B_  4096
#define C_  1000
#define P_  10
#define D_  256
#define N_  10000
#define E_  160000

typedef __attribute__((ext_vector_type(8))) short short8;
typedef __attribute__((ext_vector_type(4))) float floatx4;

#define MFMA16(a, b, c) __builtin_amdgcn_mfma_f32_16x16x32_bf16((a), (b), (c), 0, 0, 0)

// ---------------- helpers ----------------
__device__ __forceinline__ float waveReduceSum(float v){
  #pragma unroll
  for (int o = 32; o > 0; o >>= 1) v += __shfl_xor(v, o);
  return v;
}
__device__ __forceinline__ unsigned short f2bf(float f){
  unsigned int u = __float_as_uint(f);
  unsigned int r = (u + 0x7FFFu + ((u >> 16) & 1u)) >> 16;
  return (unsigned short)r;
}
__device__ __forceinline__ float bf2f(unsigned short b){
  return __uint_as_float(((unsigned int)b) << 16);
}
// DMA 16B/lane global->LDS (dest = wave-uniform base + lane*16)
__device__ __forceinline__ void gload_lds16(const void* g, void* l){
  __builtin_amdgcn_global_load_lds((const __attribute__((address_space(1))) void*)g,
                                   (__attribute__((address_space(3))) void*)l, 16, 0, 0);
}

// ---------------- prep: scatter + W split + NF split + hidden norm + zero ------
__global__ void k_prep(const int* __restrict__ src, const int* __restrict__ dst,
                       int* __restrict__ cursor, int* __restrict__ csr_src,
                       const float* __restrict__ w1, const float* __restrict__ w2,
                       unsigned short* __restrict__ w1h, unsigned short* __restrict__ w1l,
                       unsigned short* __restrict__ w2h, unsigned short* __restrict__ w2l,
                       float* __restrict__ zero_zone,
                       const float* __restrict__ nodef,
                       unsigned short* __restrict__ NFh, unsigned short* __restrict__ NFl,
                       const float* __restrict__ hidden,
                       unsigned short* __restrict__ HNh, unsigned short* __restrict__ HNl){
  int b = blockIdx.x;
  int t = threadIdx.x;
  if (b < 625){
    int e = b * 256 + t;
    if (e < E_){
      int d = dst[e];
      int p = atomicAdd(&cursor[d], 1);
      p = (p < 63) ? p : 63;
      csr_src[d * 64 + p] = src[e];
    }
  } else if (b < 1137){
    int bb = b - 625;                 // 0..511
    const float* w = (bb < 256) ? w1 : w2;
    int n = bb & 255;
    float x = w[(size_t)t * 256 + n];
    unsigned short h = f2bf(x);
    unsigned short l = f2bf(x - bf2f(h));
    if (bb < 256){ w1h[(size_t)n * 256 + t] = h; w1l[(size_t)n * 256 + t] = l; }
    else         { w2h[(size_t)n * 256 + t] = h; w2l[(size_t)n * 256 + t] = l; }
  } else if (b < 1216){
    int i = (b - 1137) * 256 + t;
    if (i < 1 + 2 * N_) zero_zone[i] = 0.f;
  } else if (b < 11216){
    size_t i = (size_t)(b - 1216) * 256 + t;
    float x = nodef[i];
    unsigned short h = f2bf(x);
    NFh[i] = h;
    NFl[i] = f2bf(x - bf2f(h));
  } else {
    int r = b - 11216;                // 0..4095
    float v = hidden[(size_t)r * 256 + t];
    float ss = waveReduceSum(v * v);
    __shared__ float red[4];
    int w = t >> 6;
    if ((t & 63) == 0) red[w] = ss;
    __syncthreads();
    float tot = red[0] + red[1] + red[2] + red[3];
    float nrm = fmaxf(sqrtf(tot), 1e-12f);
    float x = v / nrm;
    unsigned short h = f2bf(x);
    HNh[(size_t)r * 256 + t] = h;
    HNl[(size_t)r * 256 + t] = f2bf(x - bf2f(h));
  }
}

// ---------------- MFMA GEMM: out[M,256] = A_bf16split[M,256] @ W[256,256] ------
__global__ __launch_bounds__(64) void k_gemm_mfma(
    const unsigned short* __restrict__ Ah, const unsigned short* __restrict__ Al,
    const unsigned short* __restrict__ Wh, const unsigned short* __restrict__ Wl,
    float* __restrict__ outp){
  int lane = threadIdx.x;
  int l15 = lane & 15, lq = lane >> 4;
  int rb = blockIdx.x * 64;
  int nb = blockIdx.y * 32;

  floatx4 acc[4][2];
  #pragma unroll
  for (int mt = 0; mt < 4; ++mt)
    #pragma unroll
    for (int nt = 0; nt < 2; ++nt) acc[mt][nt] = (floatx4){0.f,0.f,0.f,0.f};

  int arow[4];
  #pragma unroll
  for (int mt = 0; mt < 4; ++mt){
    int r = rb + mt * 16 + l15;
    arow[mt] = (r < N_) ? r : (N_ - 1);
  }
  for (int kc = 0; kc < 256; kc += 32){
    short8 ah[4], al[4], bh[2], bl[2];
    #pragma unroll
    for (int mt = 0; mt < 4; ++mt){
      size_t o = (size_t)arow[mt] * 256 + kc + lq * 8;
      ah[mt] = *(const short8*)(Ah + o);
      al[mt] = *(const short8*)(Al + o);
    }
    #pragma unroll
    for (int nt = 0; nt < 2; ++nt){
      size_t o = (size_t)(nb + nt * 16 + l15) * 256 + kc + lq * 8;
      bh[nt] = *(const short8*)(Wh + o);
      bl[nt] = *(const short8*)(Wl + o);
    }
    #pragma unroll
    for (int nt = 0; nt < 2; ++nt)
      #pragma unroll
      for (int mt = 0; mt < 4; ++mt) acc[mt][nt] = MFMA16(al[mt], bh[nt], acc[mt][nt]);
    #pragma unroll
    for (int nt = 0; nt < 2; ++nt)
      #pragma unroll
      for (int mt = 0; mt < 4; ++mt) acc[mt][nt] = MFMA16(ah[mt], bl[nt], acc[mt][nt]);
    #pragma unroll
    for (int nt = 0; nt < 2; ++nt)
      #pragma unroll
      for (int mt = 0; mt < 4; ++mt) acc[mt][nt] = MFMA16(ah[mt], bh[nt], acc[mt][nt]);
  }
  #pragma unroll
  for (int mt = 0; mt < 4; ++mt)
    #pragma unroll
    for (int r = 0; r < 4; ++r){
      int row = rb + mt * 16 + lq * 4 + r;
      if (row < N_){
        #pragma unroll
        for (int nt = 0; nt < 2; ++nt)
          outp[(size_t)row * 256 + nb + nt * 16 + l15] = acc[mt][nt][r];
      }
    }
}

// ---------------- GCN agg layer 1: 4 waves per NODE (edge-list split) ----------
// wave w gathers edges [w*16, w*16+16); partials combined via LDS; wave 0 does
// self-loop + bias + relu + bf16 split. Quarters the per-wave latency chain.
__global__ void k_agg_split(const float* __restrict__ XW, const int* __restrict__ deg,
                            const int* __restrict__ csr_src,
                            const float* __restrict__ bias,
                            unsigned short* __restrict__ Xh, unsigned short* __restrict__ Xl){
  __shared__ float4 redbuf[3][64];
  int n    = blockIdx.x;
  int wid  = threadIdx.x >> 6;
  int lane = threadIdx.x & 63;
  int c4   = lane * 4;
  int dgn  = deg[n];
  int dg   = (dgn < 64) ? dgn : 64;
  int base = wid * 16;
  int cnt  = dg - base; cnt = (cnt < 0) ? 0 : ((cnt > 16) ? 16 : cnt);
  int   esr = (lane < cnt) ? csr_src[n * 64 + base + lane] : 0;
  float is  = 1.0f / sqrtf((float)(dgn + 1));
  float en  = (1.0f / sqrtf((float)(deg[esr] + 1))) * is;
  float4 a = make_float4(0.f, 0.f, 0.f, 0.f);
  if (wid == 0){
    float4 s = *(const float4*)(XW + (size_t)n * 256 + c4);
    float w = is * is;
    a = make_float4(w * s.x, w * s.y, w * s.z, w * s.w);
  }
  int i = 0;
  for (; i + 7 < cnt; i += 8){
    int   si[8]; float ni[8];
    #pragma unroll
    for (int j = 0; j < 8; ++j){ si[j] = __shfl(esr, i+j); ni[j] = __shfl(en, i+j); }
    float4 vv[8];
    #pragma unroll
    for (int j = 0; j < 8; ++j) vv[j] = *(const float4*)(XW + (size_t)si[j] * 256 + c4);
    #pragma unroll
    for (int j = 0; j < 8; ++j){
      a.x += ni[j] * vv[j].x; a.y += ni[j] * vv[j].y;
      a.z += ni[j] * vv[j].z; a.w += ni[j] * vv[j].w;
    }
  }
  for (; i < cnt; ++i){
    int s0 = __shfl(esr, i); float n0 = __shfl(en, i);
    float4 v0 = *(const float4*)(XW + (size_t)s0 * 256 + c4);
    a.x += n0 * v0.x; a.y += n0 * v0.y; a.z += n0 * v0.z; a.w += n0 * v0.w;
  }
  if (wid) redbuf[wid - 1][lane] = a;
  __syncthreads();
  if (wid == 0){
    float4 r0 = redbuf[0][lane], r1 = redbuf[1][lane], r2 = redbuf[2][lane];
    a.x += r0.x + r1.x + r2.x; a.y += r0.y + r1.y + r2.y;
    a.z += r0.z + r1.z + r2.z; a.w += r0.w + r1.w + r2.w;
    float4 b = *(const float4*)(bias + c4);
    float x0 = fmaxf(a.x + b.x, 0.f), x1 = fmaxf(a.y + b.y, 0.f);
    float x2 = fmaxf(a.z + b.z, 0.f), x3 = fmaxf(a.w + b.w, 0.f);
    unsigned short h0 = f2bf(x0), h1 = f2bf(x1), h2 = f2bf(x2), h3 = f2bf(x3);
    ushort4 hv = make_ushort4(h0, h1, h2, h3);
    ushort4 lv = make_ushort4(f2bf(x0 - bf2f(h0)), f2bf(x1 - bf2f(h1)),
                              f2bf(x2 - bf2f(h2)), f2bf(x3 - bf2f(h3)));
    *(ushort4*)(Xh + (size_t)n * 256 + c4) = hv;
    *(ushort4*)(Xl + (size_t)n * 256 + c4) = lv;
  }
}

// ---------------- GCN agg layer 2: 4 waves/node + L2 normalize + split ---------
__global__ void k_agg_norm_split(const float* __restrict__ XW, const int* __restrict__ deg,
                                 const int* __restrict__ csr_src,
                                 const float* __restrict__ bias,
                                 unsigned short* __restrict__ Ph, unsigned short* __restrict__ Pl){
  __shared__ float4 redbuf[3][64];
  int n    = blockIdx.x;
  int wid  = threadIdx.x >> 6;
  int lane = threadIdx.x & 63;
  int c4   = lane * 4;
  int dgn  = deg[n];
  int dg   = (dgn < 64) ? dgn : 64;
  int base = wid * 16;
  int cnt  = dg - base; cnt = (cnt < 0) ? 0 : ((cnt > 16) ? 16 : cnt);
  int   esr = (lane < cnt) ? csr_src[n * 64 + base + lane] : 0;
  float is  = 1.0f / sqrtf((float)(dgn + 1));
  float en  = (1.0f / sqrtf((float)(deg[esr] + 1))) * is;
  float4 a = make_float4(0.f, 0.f, 0.f, 0.f);
  if (wid == 0){
    float4 s = *(const float4*)(XW + (size_t)n * 256 + c4);
    float w = is * is;
    a = make_float4(w * s.x, w * s.y, w * s.z, w * s.w);
  }
  int i = 0;
  for (; i + 7 < cnt; i += 8){
    int   si[8]; float ni[8];
    #pragma unroll
    for (int j = 0; j < 8; ++j){ si[j] = __shfl(esr, i+j); ni[j] = __shfl(en, i+j); }
    float4 vv[8];
    #pragma unroll
    for (int j = 0; j < 8; ++j) vv[j] = *(const float4*)(XW + (size_t)si[j] * 256 + c4);
    #pragma unroll
    for (int j = 0; j < 8; ++j){
      a.x += ni[j] * vv[j].x; a.y += ni[j] * vv[j].y;
      a.z += ni[j] * vv[j].z; a.w += ni[j] * vv[j].w;
    }
  }
  for (; i < cnt; ++i){
    int s0 = __shfl(esr, i); float n0 = __shfl(en, i);
    float4 v0 = *(const float4*)(XW + (size_t)s0 * 256 + c4);
    a.x += n0 * v0.x; a.y += n0 * v0.y; a.z += n0 * v0.z; a.w += n0 * v0.w;
  }
  if (wid) redbuf[wid - 1][lane] = a;
  __syncthreads();
  if (wid == 0){
    float4 r0 = redbuf[0][lane], r1 = redbuf[1][lane], r2 = redbuf[2][lane];
    a.x += r0.x + r1.x + r2.x; a.y += r0.y + r1.y + r2.y;
    a.z += r0.z + r1.z + r2.z; a.w += r0.w + r1.w + r2.w;
    float4 b = *(const float4*)(bias + c4);
    float x0 = fmaxf(a.x + b.x, 0.f), x1 = fmaxf(a.y + b.y, 0.f);
    float x2 = fmaxf(a.z + b.z, 0.f), x3 = fmaxf(a.w + b.w, 0.f);
    float ss = x0*x0 + x1*x1 + x2*x2 + x3*x3;
    float tot = waveReduceSum(ss);
    float nrm = fmaxf(sqrtf(tot), 1e-12f);
    x0 /= nrm; x1 /= nrm; x2 /= nrm; x3 /= nrm;
    unsigned short h0 = f2bf(x0), h1 = f2bf(x1), h2 = f2bf(x2), h3 = f2bf(x3);
    ushort4 hv = make_ushort4(h0, h1, h2, h3);
    ushort4 lv = make_ushort4(f2bf(x0 - bf2f(h0)), f2bf(x1 - bf2f(h1)),
                              f2bf(x2 - bf2f(h2)), f2bf(x3 - bf2f(h3)));
    *(ushort4*)(Ph + (size_t)n * 256 + c4) = hv;
    *(ushort4*)(Pl + (size_t)n * 256 + c4) = lv;
  }
}

// ---------------- MFMA sim GEMM (3-term bf16 split) + per-class max ------------
// 16x16 supertile XCD swizzle (R17: FETCH 188->29 MB). WAVE STAGGER: odd waves
// run nt-group {3,4} before {0,1,2} -> LDS-read phase of half the waves overlaps
// the MFMA phase of the other half (pipes de-phase-aligned).
// LAW (R6/R11/R13): this tile NEEDS launch_bounds(256,4).
__global__ __launch_bounds__(256, 4) void k_sim_max(
    const unsigned short* __restrict__ HNh, const unsigned short* __restrict__ HNl,
    const unsigned short* __restrict__ PNh, const unsigned short* __restrict__ PNl,
    float* __restrict__ out, unsigned char* __restrict__ idxb){
  __shared__ __align__(16) char smem[20736];

  int nblk = blockIdx.x;
  int st = nblk >> 8, wi = nblk & 255;
  int bx = (st & 7) * 16 + (wi & 15);     // class group 0..127
  int by = (st >> 3) * 16 + (wi >> 4);    // row group 0..31
  if (bx >= 125) return;                   // uniform early-exit (before any barrier)

  int tid  = threadIdx.x;
  int wid  = tid >> 6;
  int lane = tid & 63;
  int l15  = lane & 15, lq = lane >> 4;
  int rbw  = by * 128 + wid * 32;
  int cb80 = bx * 80;

  int swz  = (l15 >> 1) & 3;
  int srow = lane >> 2;
  int skq  = (lane & 3) ^ ((lane >> 3) & 3);

  floatx4 acc[2][5];
  #pragma unroll
  for (int mt = 0; mt < 2; ++mt)
    #pragma unroll
    for (int nt = 0; nt < 5; ++nt) acc[mt][nt] = (floatx4){0.f,0.f,0.f,0.f};

  const unsigned short* a0h = HNh + (size_t)(rbw + l15) * 256 + lq * 8;
  const unsigned short* a0l = HNl + (size_t)(rbw + l15) * 256 + lq * 8;

  auto stage1 = [&](int kc, int pb, int c){
    int bsel = (c >= 5) ? 1 : 0;
    int s = c - bsel * 5;
    int row = s * 16 + srow;
    const unsigned short* gp = (bsel ? PNl : PNh)
        + (size_t)(cb80 + row) * 256 + kc + skq * 8;
    char* lp = smem + pb * 10240 + bsel * 5120 + s * 1024;
    gload_lds16(gp, lp);
  };
  auto stageAll = [&](int kc, int pb){
    stage1(kc, pb, wid);
    stage1(kc, pb, wid + 4);
    if (wid < 2) stage1(kc, pb, wid + 8);
  };

  stageAll(0, 0);
  short8 ah[2], al[2];
  #pragma unroll
  for (int mt = 0; mt < 2; ++mt){
    ah[mt] = *(const short8*)(a0h + (size_t)mt * 4096);
    al[mt] = *(const short8*)(a0l + (size_t)mt * 4096);
  }
  __syncthreads();

  int p = 0;
  for (int kc = 0; kc < 256; kc += 32){
    const unsigned short* Bh = (const unsigned short*)(smem + p * 10240);
    const unsigned short* Bl = Bh + 2560;
    short8 ah2[2], al2[2];
    if (kc < 224){
      stageAll(kc + 32, p ^ 1);
      #pragma unroll
      for (int mt = 0; mt < 2; ++mt){
        ah2[mt] = *(const short8*)(a0h + (size_t)mt * 4096 + kc + 32);
        al2[mt] = *(const short8*)(a0l + (size_t)mt * 4096 + kc + 32);
      }
    }
    auto group012 = [&](){
      int r0 = (0 * 16 + l15) * 32 + (lq ^ swz) * 8;
      int r1 = (1 * 16 + l15) * 32 + (lq ^ swz) * 8;
      int r2 = (2 * 16 + l15) * 32 + (lq ^ swz) * 8;
      short8 bh0 = *(const short8*)(Bh + r0), bl0 = *(const short8*)(Bl + r0);
      short8 bh1 = *(const short8*)(Bh + r1), bl1 = *(const short8*)(Bl + r1);
      short8 bh2 = *(const short8*)(Bh + r2), bl2 = *(const short8*)(Bl + r2);
      acc[0][0] = MFMA16(al[0], bh0, acc[0][0]);
      acc[1][0] = MFMA16(al[1], bh0, acc[1][0]);
      acc[0][1] = MFMA16(al[0], bh1, acc[0][1]);
      acc[1][1] = MFMA16(al[1], bh1, acc[1][1]);
      acc[0][2] = MFMA16(al[0], bh2, acc[0][2]);
      acc[1][2] = MFMA16(al[1], bh2, acc[1][2]);
      acc[0][0] = MFMA16(ah[0], bl0, acc[0][0]);
      acc[1][0] = MFMA16(ah[1], bl0, acc[1][0]);
      acc[0][1] = MFMA16(ah[0], bl1, acc[0][1]);
      acc[1][1] = MFMA16(ah[1], bl1, acc[1][1]);
      acc[0][2] = MFMA16(ah[0], bl2, acc[0][2]);
      acc[1][2] = MFMA16(ah[1], bl2, acc[1][2]);
      acc[0][0] = MFMA16(ah[0], bh0, acc[0][0]);
      acc[1][0] = MFMA16(ah[1], bh0, acc[1][0]);
      acc[0][1] = MFMA16(ah[0], bh1, acc[0][1]);
      acc[1][1] = MFMA16(ah[1], bh1, acc[1][1]);
      acc[0][2] = MFMA16(ah[0], bh2, acc[0][2]);
      acc[1][2] = MFMA16(ah[1], bh2, acc[1][2]);
    };
    auto group34 = [&](){
      int r3 = (3 * 16 + l15) * 32 + (lq ^ swz) * 8;
      int r4 = (4 * 16 + l15) * 32 + (lq ^ swz) * 8;
      short8 bh3 = *(const short8*)(Bh + r3), bl3 = *(const short8*)(Bl + r3);
      short8 bh4 = *(const short8*)(Bh + r4), bl4 = *(const short8*)(Bl + r4);
      acc[0][3] = MFMA16(al[0], bh3, acc[0][3]);
      acc[1][3] = MFMA16(al[1], bh3, acc[1][3]);
      acc[0][4] = MFMA16(al[0], bh4, acc[0][4]);
      acc[1][4] = MFMA16(al[1], bh4, acc[1][4]);
      acc[0][3] = MFMA16(ah[0], bl3, acc[0][3]);
      acc[1][3] = MFMA16(ah[1], bl3, acc[1][3]);
      acc[0][4] = MFMA16(ah[0], bl4, acc[0][4]);
      acc[1][4] = MFMA16(ah[1], bl4, acc[1][4]);
      acc[0][3] = MFMA16(ah[0], bh3, acc[0][3]);
      acc[1][3] = MFMA16(ah[1], bh3, acc[1][3]);
      acc[0][4] = MFMA16(ah[0], bh4, acc[0][4]);
      acc[1][4] = MFMA16(ah[1], bh4, acc[1][4]);
    };
    if ((wid & 1) == 0){ group012(); group34(); }
    else               { group34(); group012(); }
    ah[0] = ah2[0]; ah[1] = ah2[1];
    al[0] = al2[0]; al[1] = al2[1];
    __syncthreads();
    p ^= 1;
  }

  // epilogue: per-wave 16x81 scratch overlaying the (dead) B buffers.
  float* redw = (float*)smem + wid * 1296;
  #pragma unroll
  for (int mt = 0; mt < 2; ++mt){
    #pragma unroll
    for (int nt = 0; nt < 5; ++nt)
      #pragma unroll
      for (int r = 0; r < 4; ++r)
        redw[(lq * 4 + r) * 81 + nt * 16 + l15] = acc[mt][nt][r];
    int row = lane >> 2;
    int q   = lane & 3;
    const float* basep = redw + row * 81 + q * 20;
    float vs[2]; int is[2];
    #pragma unroll
    for (int cc = 0; cc < 2; ++cc){
      float m = 0.5f * (1.0f + basep[cc * 10]); int mi = 0;
      #pragma unroll
      for (int p2 = 1; p2 < 10; ++p2){
        float v = 0.5f * (1.0f + basep[cc * 10 + p2]);
        if (v > m){ m = v; mi = p2; }
      }
      vs[cc] = m; is[cc] = mi;
    }
    int grow = rbw + mt * 16 + row;
    int gcol = bx * 8 + q * 2;
    *(float2*)(out + (size_t)grow * 1000 + gcol) = make_float2(vs[0], vs[1]);
    idxb[(size_t)grow * 1000 + gcol]     = (unsigned char)is[0];
    idxb[(size_t)grow * 1000 + gcol + 1] = (unsigned char)is[1];
  }
}

// ---------------- row pass (ILP softmax) + colsum tail (no fences) -------------
__global__ void k_row_pass(const float* __restrict__ out, const unsigned char* __restrict__ idxb,
                           const int* __restrict__ labels, int* __restrict__ cnt,
                           float* __restrict__ ce_sum, float* __restrict__ pos_usage,
                           float* __restrict__ neg_usage,
                           const unsigned short* __restrict__ Ph,
                           const unsigned short* __restrict__ Pl,
                           float* __restrict__ svec){
  int blk = blockIdx.x;
  if (blk >= 1024){
    int t = threadIdx.x;
    int r0 = (blk - 1024) * 100;
    float acc = 0.f;
    for (int rr = r0; rr < r0 + 100; ++rr)
      acc += bf2f(Ph[(size_t)rr * 256 + t]) + bf2f(Pl[(size_t)rr * 256 + t]);
    atomicAdd(&svec[t], acc);
    return;
  }
  int b = blk * 4 + (threadIdx.x >> 6);
  int lane = threadIdx.x & 63;
  const float* row = out + (size_t)b * 1000;
  float v[16];
  #pragma unroll
  for (int j = 0; j < 4; ++j){
    int f4 = j * 64 + lane;
    if (f4 < 250){
      float4 t = *(const float4*)(row + f4 * 4);
      v[j*4+0] = t.x; v[j*4+1] = t.y; v[j*4+2] = t.z; v[j*4+3] = t.w;
    } else {
      v[j*4+0] = v[j*4+1] = v[j*4+2] = v[j*4+3] = -INFINITY;
    }
  }
  float m = -INFINITY; int mi = 0x7fffffff;
  #pragma unroll
  for (int j = 0; j < 4; ++j)
    #pragma unroll
    for (int k = 0; k < 4; ++k){
      float x = v[j*4+k];
      if (x > m){ m = x; mi = (j * 64 + lane) * 4 + k; }
    }
  #pragma unroll
  for (int o = 32; o > 0; o >>= 1){
    float m2 = __shfl_xor(m, o);
    int   i2 = __shfl_xor(mi, o);
    if (m2 > m || (m2 == m && i2 < mi)){ m = m2; mi = i2; }
  }
  float s = 0.f;
  #pragma unroll
  for (int t = 0; t < 16; ++t) s += __expf(v[t] - m);
  s = waveReduceSum(s);
  if (lane == 0){
    int lab = labels[b];
    float true_score = row[lab];
    float per_ce = m + __logf(s) - true_score;
    bool mask = (true_score - m) > -0.1f;
    if (mask){ atomicAdd(cnt, 1); atomicAdd(ce_sum, per_ce); }
    int pi = idxb[(size_t)b * 1000 + lab];
    atomicAdd(&pos_usage[lab * P_ + pi], 1.f);
    if (mi != lab){
      int ni = idxb[(size_t)b * 1000 + mi];
      atomicAdd(&neg_usage[mi * P_ + ni], 1.f);
    }
  }
}

// ---------------- finalize loss ----------------
__global__ void k_finalize(const float* __restrict__ s, const int* __restrict__ cnt,
                           const float* __restrict__ ce_sum, float* __restrict__ loss_out){
  int t = threadIdx.x;
  float v = s[t];
  float ss = waveReduceSum(v * v);
  __shared__ float red[4];
  if ((t & 63) == 0) red[t >> 6] = ss;
  __syncthreads();
  if (t == 0){
    float tot = red[0] + red[1] + red[2] + red[3];
    float disp = -tot / 1.0e8f;
    int c = *cnt;
    float total = (c == 0) ? 0.f
                : (*ce_sum / (float)(c < 1 ? 1 : c) + 0.1f * disp);
    *loss_out = total;
  }
}

// ---------------- launcher ----------------
extern "C" void kernel_launch(void* const* d_in, const int* in_sizes, int n_in,
                              void* d_out, int out_size, void* d_ws, size_t ws_size,
                              hipStream_t stream){
  const float* hidden = (const float*)d_in[0];
  const int*   labels = (const int*)  d_in[1];
  const int*   eidx   = (const int*)  d_in[2];
  const float* nodef  = (const float*)d_in[3];
  const float* w1     = (const float*)d_in[4];
  const float* b1     = (const float*)d_in[5];
  const float* w2     = (const float*)d_in[6];
  const float* b2     = (const float*)d_in[7];

  float* out       = (float*)d_out;
  float* loss_out  = out + (size_t)B_ * C_;
  float* pos_usage = loss_out + 1;
  float* neg_usage = pos_usage + N_;

  const int* srcp = eidx;
  const int* dstp = eidx + E_;

  char* base = (char*)d_ws;
  size_t off = 0;
  auto alloc = [&](size_t bytes) -> char* {
    char* p = base + off;
    off = (off + bytes + 255) & ~(size_t)255;
    return p;
  };
  int*   cursor  = (int*)  alloc((size_t)N_ * 4);
  float* svec    = (float*)alloc(256 * 4);
  int*   cnt     = (int*)  alloc(4);
  float* ce_sum  = (float*)alloc(4);
  size_t zero_bytes = off;
  int*   csr_src   = (int*)  alloc((size_t)N_ * 64 * 4);
  float* XW        = (float*)alloc((size_t)N_ * 256 * 4);
  unsigned short* NFh = (unsigned short*)alloc((size_t)N_ * 256 * 2);
  unsigned short* NFl = (unsigned short*)alloc((size_t)N_ * 256 * 2);
  unsigned short* Xh  = (unsigned short*)alloc((size_t)N_ * 256 * 2);
  unsigned short* Xl  = (unsigned short*)alloc((size_t)N_ * 256 * 2);
  unsigned short* Ph  = (unsigned short*)alloc((size_t)N_ * 256 * 2);
  unsigned short* Pl  = (unsigned short*)alloc((size_t)N_ * 256 * 2);
  unsigned short* W1h = (unsigned short*)alloc(256 * 256 * 2);
  unsigned short* W1l = (unsigned short*)alloc(256 * 256 * 2);
  unsigned short* W2h = (unsigned short*)alloc(256 * 256 * 2);
  unsigned short* W2l = (unsigned short*)alloc(256 * 256 * 2);
  unsigned short* HNh = (unsigned short*)alloc((size_t)B_ * 256 * 2);
  unsigned short* HNl = (unsigned short*)alloc((size_t)B_ * 256 * 2);
  unsigned char* idxb = (unsigned char*)alloc((size_t)B_ * C_);

  hipMemsetAsync(base, 0, zero_bytes, stream);

  k_prep<<<15312, 256, 0, stream>>>(srcp, dstp, cursor, csr_src,
                                    w1, w2, W1h, W1l, W2h, W2l, loss_out,
                                    nodef, NFh, NFl, hidden, HNh, HNl);

  dim3 ggrid(157, 8);
  k_gemm_mfma<<<ggrid, 64, 0, stream>>>(NFh, NFl, W1h, W1l, XW);
  k_agg_split<<<N_, 256, 0, stream>>>(XW, cursor, csr_src, b1, Xh, Xl);
  k_gemm_mfma<<<ggrid, 64, 0, stream>>>(Xh, Xl, W2h, W2l, XW);
  k_agg_norm_split<<<N_, 256, 0, stream>>>(XW, cursor, csr_src, b2, Ph, Pl);

  k_sim_max<<<4096, 256, 0, stream>>>(HNh, HNl, Ph, Pl, out, idxb);

  k_row_pass<<<1124, 256, 0, stream>>>(out, idxb, labels, cnt, ce_sum,
                                       pos_usage, neg_usage, Ph, Pl, svec);
  k_finalize<<<1, 256, 0, stream>>>(svec, cnt, ce_sum, loss_out);
}

// Round 19
// 317.199 us; speedup vs baseline: 1.0342x; 1.0342x over previous
//
#include <hip/hip_runtime.h>
#include <math.h>

#define B_  4096
#define C_  1000
#define P_  10
#define D_  256
#define N_  10000
#define E_  160000

typedef __attribute__((ext_vector_type(8))) short short8;
typedef __attribute__((ext_vector_type(4))) float floatx4;

#define MFMA16(a, b, c) __builtin_amdgcn_mfma_f32_16x16x32_bf16((a), (b), (c), 0, 0, 0)

// ---------------- helpers ----------------
__device__ __forceinline__ float waveReduceSum(float v){
  #pragma unroll
  for (int o = 32; o > 0; o >>= 1) v += __shfl_xor(v, o);
  return v;
}
__device__ __forceinline__ unsigned short f2bf(float f){
  unsigned int u = __float_as_uint(f);
  unsigned int r = (u + 0x7FFFu + ((u >> 16) & 1u)) >> 16;
  return (unsigned short)r;
}
__device__ __forceinline__ float bf2f(unsigned short b){
  return __uint_as_float(((unsigned int)b) << 16);
}
// DMA 16B/lane global->LDS (dest = wave-uniform base + lane*16)
__device__ __forceinline__ void gload_lds16(const void* g, void* l){
  __builtin_amdgcn_global_load_lds((const __attribute__((address_space(1))) void*)g,
                                   (__attribute__((address_space(3))) void*)l, 16, 0, 0);
}

// ---------------- prep: scatter + W split + NF split + hidden norm + zero ------
__global__ void k_prep(const int* __restrict__ src, const int* __restrict__ dst,
                       int* __restrict__ cursor, int* __restrict__ csr_src,
                       const float* __restrict__ w1, const float* __restrict__ w2,
                       unsigned short* __restrict__ w1h, unsigned short* __restrict__ w1l,
                       unsigned short* __restrict__ w2h, unsigned short* __restrict__ w2l,
                       float* __restrict__ zero_zone,
                       const float* __restrict__ nodef,
                       unsigned short* __restrict__ NFh, unsigned short* __restrict__ NFl,
                       const float* __restrict__ hidden,
                       unsigned short* __restrict__ HNh, unsigned short* __restrict__ HNl){
  int b = blockIdx.x;
  int t = threadIdx.x;
  if (b < 625){
    int e = b * 256 + t;
    if (e < E_){
      int d = dst[e];
      int p = atomicAdd(&cursor[d], 1);
      p = (p < 63) ? p : 63;
      csr_src[d * 64 + p] = src[e];
    }
  } else if (b < 1137){
    int bb = b - 625;                 // 0..511
    const float* w = (bb < 256) ? w1 : w2;
    int n = bb & 255;
    float x = w[(size_t)t * 256 + n];
    unsigned short h = f2bf(x);
    unsigned short l = f2bf(x - bf2f(h));
    if (bb < 256){ w1h[(size_t)n * 256 + t] = h; w1l[(size_t)n * 256 + t] = l; }
    else         { w2h[(size_t)n * 256 + t] = h; w2l[(size_t)n * 256 + t] = l; }
  } else if (b < 1216){
    int i = (b - 1137) * 256 + t;
    if (i < 1 + 2 * N_) zero_zone[i] = 0.f;
  } else if (b < 11216){
    size_t i = (size_t)(b - 1216) * 256 + t;
    float x = nodef[i];
    unsigned short h = f2bf(x);
    NFh[i] = h;
    NFl[i] = f2bf(x - bf2f(h));
  } else {
    int r = b - 11216;                // 0..4095
    float v = hidden[(size_t)r * 256 + t];
    float ss = waveReduceSum(v * v);
    __shared__ float red[4];
    int w = t >> 6;
    if ((t & 63) == 0) red[w] = ss;
    __syncthreads();
    float tot = red[0] + red[1] + red[2] + red[3];
    float nrm = fmaxf(sqrtf(tot), 1e-12f);
    float x = v / nrm;
    unsigned short h = f2bf(x);
    HNh[(size_t)r * 256 + t] = h;
    HNl[(size_t)r * 256 + t] = f2bf(x - bf2f(h));
  }
}

// ---------------- MFMA GEMM: out[M,256] = A_bf16split[M,256] @ W[256,256] ------
__global__ __launch_bounds__(64) void k_gemm_mfma(
    const unsigned short* __restrict__ Ah, const unsigned short* __restrict__ Al,
    const unsigned short* __restrict__ Wh, const unsigned short* __restrict__ Wl,
    float* __restrict__ outp){
  int lane = threadIdx.x;
  int l15 = lane & 15, lq = lane >> 4;
  int rb = blockIdx.x * 64;
  int nb = blockIdx.y * 32;

  floatx4 acc[4][2];
  #pragma unroll
  for (int mt = 0; mt < 4; ++mt)
    #pragma unroll
    for (int nt = 0; nt < 2; ++nt) acc[mt][nt] = (floatx4){0.f,0.f,0.f,0.f};

  int arow[4];
  #pragma unroll
  for (int mt = 0; mt < 4; ++mt){
    int r = rb + mt * 16 + l15;
    arow[mt] = (r < N_) ? r : (N_ - 1);
  }
  for (int kc = 0; kc < 256; kc += 32){
    short8 ah[4], al[4], bh[2], bl[2];
    #pragma unroll
    for (int mt = 0; mt < 4; ++mt){
      size_t o = (size_t)arow[mt] * 256 + kc + lq * 8;
      ah[mt] = *(const short8*)(Ah + o);
      al[mt] = *(const short8*)(Al + o);
    }
    #pragma unroll
    for (int nt = 0; nt < 2; ++nt){
      size_t o = (size_t)(nb + nt * 16 + l15) * 256 + kc + lq * 8;
      bh[nt] = *(const short8*)(Wh + o);
      bl[nt] = *(const short8*)(Wl + o);
    }
    #pragma unroll
    for (int nt = 0; nt < 2; ++nt)
      #pragma unroll
      for (int mt = 0; mt < 4; ++mt) acc[mt][nt] = MFMA16(al[mt], bh[nt], acc[mt][nt]);
    #pragma unroll
    for (int nt = 0; nt < 2; ++nt)
      #pragma unroll
      for (int mt = 0; mt < 4; ++mt) acc[mt][nt] = MFMA16(ah[mt], bl[nt], acc[mt][nt]);
    #pragma unroll
    for (int nt = 0; nt < 2; ++nt)
      #pragma unroll
      for (int mt = 0; mt < 4; ++mt) acc[mt][nt] = MFMA16(ah[mt], bh[nt], acc[mt][nt]);
  }
  #pragma unroll
  for (int mt = 0; mt < 4; ++mt)
    #pragma unroll
    for (int r = 0; r < 4; ++r){
      int row = rb + mt * 16 + lq * 4 + r;
      if (row < N_){
        #pragma unroll
        for (int nt = 0; nt < 2; ++nt)
          outp[(size_t)row * 256 + nb + nt * 16 + l15] = acc[mt][nt][r];
      }
    }
}

// ---------------- GCN agg + bias + relu -> bf16 split (layer 1) ----------------
// 8x unrolled gather, dual accumulators.
__global__ void k_agg_split(const float* __restrict__ XW, const int* __restrict__ deg,
                            const int* __restrict__ csr_src,
                            const float* __restrict__ bias,
                            unsigned short* __restrict__ Xh, unsigned short* __restrict__ Xl){
  int n    = blockIdx.x * 4 + (threadIdx.x >> 6);
  int lane = threadIdx.x & 63;
  int c4   = lane * 4;
  int dgn = deg[n];
  int dg = (dgn < 64) ? dgn : 64;
  int   esr = (lane < dg) ? csr_src[n * 64 + lane] : 0;
  float is  = 1.0f / sqrtf((float)(dgn + 1));
  float en  = (1.0f / sqrtf((float)(deg[esr] + 1))) * is;
  float4 s = *(const float4*)(XW + (size_t)n * 256 + c4);
  float w = is * is;
  float4 a = make_float4(w * s.x, w * s.y, w * s.z, w * s.w);
  float4 a2 = make_float4(0.f, 0.f, 0.f, 0.f);
  int i = 0;
  for (; i + 7 < dg; i += 8){
    int   si[8]; float ni[8];
    #pragma unroll
    for (int j = 0; j < 8; ++j){ si[j] = __shfl(esr, i+j); ni[j] = __shfl(en, i+j); }
    float4 vv[8];
    #pragma unroll
    for (int j = 0; j < 8; ++j) vv[j] = *(const float4*)(XW + (size_t)si[j] * 256 + c4);
    #pragma unroll
    for (int j = 0; j < 4; ++j){
      a.x  += ni[j]   * vv[j].x;   a.y  += ni[j]   * vv[j].y;
      a.z  += ni[j]   * vv[j].z;   a.w  += ni[j]   * vv[j].w;
      a2.x += ni[j+4] * vv[j+4].x; a2.y += ni[j+4] * vv[j+4].y;
      a2.z += ni[j+4] * vv[j+4].z; a2.w += ni[j+4] * vv[j+4].w;
    }
  }
  for (; i < dg; ++i){
    int s0 = __shfl(esr, i); float n0 = __shfl(en, i);
    float4 v0 = *(const float4*)(XW + (size_t)s0 * 256 + c4);
    a.x += n0 * v0.x; a.y += n0 * v0.y; a.z += n0 * v0.z; a.w += n0 * v0.w;
  }
  a.x += a2.x; a.y += a2.y; a.z += a2.z; a.w += a2.w;
  float4 b = *(const float4*)(bias + c4);
  float x0 = fmaxf(a.x + b.x, 0.f), x1 = fmaxf(a.y + b.y, 0.f);
  float x2 = fmaxf(a.z + b.z, 0.f), x3 = fmaxf(a.w + b.w, 0.f);
  unsigned short h0 = f2bf(x0), h1 = f2bf(x1), h2 = f2bf(x2), h3 = f2bf(x3);
  ushort4 hv = make_ushort4(h0, h1, h2, h3);
  ushort4 lv = make_ushort4(f2bf(x0 - bf2f(h0)), f2bf(x1 - bf2f(h1)),
                            f2bf(x2 - bf2f(h2)), f2bf(x3 - bf2f(h3)));
  *(ushort4*)(Xh + (size_t)n * 256 + c4) = hv;
  *(ushort4*)(Xl + (size_t)n * 256 + c4) = lv;
}

// ---------------- GCN agg + bias + relu + L2 normalize -> bf16 split (layer 2) --
__global__ void k_agg_norm_split(const float* __restrict__ XW, const int* __restrict__ deg,
                                 const int* __restrict__ csr_src,
                                 const float* __restrict__ bias,
                                 unsigned short* __restrict__ Ph, unsigned short* __restrict__ Pl){
  int n    = blockIdx.x * 4 + (threadIdx.x >> 6);
  int lane = threadIdx.x & 63;
  int c4   = lane * 4;
  int dgn = deg[n];
  int dg = (dgn < 64) ? dgn : 64;
  int   esr = (lane < dg) ? csr_src[n * 64 + lane] : 0;
  float is  = 1.0f / sqrtf((float)(dgn + 1));
  float en  = (1.0f / sqrtf((float)(deg[esr] + 1))) * is;
  float4 s = *(const float4*)(XW + (size_t)n * 256 + c4);
  float w = is * is;
  float4 a = make_float4(w * s.x, w * s.y, w * s.z, w * s.w);
  float4 a2 = make_float4(0.f, 0.f, 0.f, 0.f);
  int i = 0;
  for (; i + 7 < dg; i += 8){
    int   si[8]; float ni[8];
    #pragma unroll
    for (int j = 0; j < 8; ++j){ si[j] = __shfl(esr, i+j); ni[j] = __shfl(en, i+j); }
    float4 vv[8];
    #pragma unroll
    for (int j = 0; j < 8; ++j) vv[j] = *(const float4*)(XW + (size_t)si[j] * 256 + c4);
    #pragma unroll
    for (int j = 0; j < 4; ++j){
      a.x  += ni[j]   * vv[j].x;   a.y  += ni[j]   * vv[j].y;
      a.z  += ni[j]   * vv[j].z;   a.w  += ni[j]   * vv[j].w;
      a2.x += ni[j+4] * vv[j+4].x; a2.y += ni[j+4] * vv[j+4].y;
      a2.z += ni[j+4] * vv[j+4].z; a2.w += ni[j+4] * vv[j+4].w;
    }
  }
  for (; i < dg; ++i){
    int s0 = __shfl(esr, i); float n0 = __shfl(en, i);
    float4 v0 = *(const float4*)(XW + (size_t)s0 * 256 + c4);
    a.x += n0 * v0.x; a.y += n0 * v0.y; a.z += n0 * v0.z; a.w += n0 * v0.w;
  }
  a.x += a2.x; a.y += a2.y; a.z += a2.z; a.w += a2.w;
  float4 b = *(const float4*)(bias + c4);
  float x0 = fmaxf(a.x + b.x, 0.f), x1 = fmaxf(a.y + b.y, 0.f);
  float x2 = fmaxf(a.z + b.z, 0.f), x3 = fmaxf(a.w + b.w, 0.f);
  float ss = x0*x0 + x1*x1 + x2*x2 + x3*x3;
  float tot = waveReduceSum(ss);
  float nrm = fmaxf(sqrtf(tot), 1e-12f);
  x0 /= nrm; x1 /= nrm; x2 /= nrm; x3 /= nrm;
  unsigned short h0 = f2bf(x0), h1 = f2bf(x1), h2 = f2bf(x2), h3 = f2bf(x3);
  ushort4 hv = make_ushort4(h0, h1, h2, h3);
  ushort4 lv = make_ushort4(f2bf(x0 - bf2f(h0)), f2bf(x1 - bf2f(h1)),
                            f2bf(x2 - bf2f(h2)), f2bf(x3 - bf2f(h3)));
  *(ushort4*)(Ph + (size_t)n * 256 + c4) = hv;
  *(ushort4*)(Pl + (size_t)n * 256 + c4) = lv;
}

// ---------------- MFMA sim GEMM (3-term bf16 split) + per-class max ------------
// 1D grid 4096 with 16x16 SUPERTILE SWIZZLE (measured R17: FETCH 188->29 MB,
// sim 97->89). NO wave stagger (R18: stagger raised VGPR 60->64, spilled,
// regressed to 95.5). Body = measured-best configuration.
// LAW (R6/R11/R13): this tile NEEDS launch_bounds(256,4).
__global__ __launch_bounds__(256, 4) void k_sim_max(
    const unsigned short* __restrict__ HNh, const unsigned short* __restrict__ HNl,
    const unsigned short* __restrict__ PNh, const unsigned short* __restrict__ PNl,
    float* __restrict__ out, unsigned char* __restrict__ idxb){
  __shared__ __align__(16) char smem[20736];

  int nblk = blockIdx.x;
  int st = nblk >> 8, wi = nblk & 255;
  int bx = (st & 7) * 16 + (wi & 15);     // class group 0..127
  int by = (st >> 3) * 16 + (wi >> 4);    // row group 0..31
  if (bx >= 125) return;                   // uniform early-exit (before any barrier)

  int tid  = threadIdx.x;
  int wid  = tid >> 6;
  int lane = tid & 63;
  int l15  = lane & 15, lq = lane >> 4;
  int rbw  = by * 128 + wid * 32;
  int cb80 = bx * 80;

  int swz  = (l15 >> 1) & 3;
  int srow = lane >> 2;
  int skq  = (lane & 3) ^ ((lane >> 3) & 3);

  floatx4 acc[2][5];
  #pragma unroll
  for (int mt = 0; mt < 2; ++mt)
    #pragma unroll
    for (int nt = 0; nt < 5; ++nt) acc[mt][nt] = (floatx4){0.f,0.f,0.f,0.f};

  const unsigned short* a0h = HNh + (size_t)(rbw + l15) * 256 + lq * 8;
  const unsigned short* a0l = HNl + (size_t)(rbw + l15) * 256 + lq * 8;

  auto stage1 = [&](int kc, int pb, int c){
    int bsel = (c >= 5) ? 1 : 0;
    int s = c - bsel * 5;
    int row = s * 16 + srow;
    const unsigned short* gp = (bsel ? PNl : PNh)
        + (size_t)(cb80 + row) * 256 + kc + skq * 8;
    char* lp = smem + pb * 10240 + bsel * 5120 + s * 1024;
    gload_lds16(gp, lp);
  };
  auto stageAll = [&](int kc, int pb){
    stage1(kc, pb, wid);
    stage1(kc, pb, wid + 4);
    if (wid < 2) stage1(kc, pb, wid + 8);
  };

  stageAll(0, 0);
  short8 ah[2], al[2];
  #pragma unroll
  for (int mt = 0; mt < 2; ++mt){
    ah[mt] = *(const short8*)(a0h + (size_t)mt * 4096);
    al[mt] = *(const short8*)(a0l + (size_t)mt * 4096);
  }
  __syncthreads();

  int p = 0;
  for (int kc = 0; kc < 256; kc += 32){
    const unsigned short* Bh = (const unsigned short*)(smem + p * 10240);
    const unsigned short* Bl = Bh + 2560;
    short8 ah2[2], al2[2];
    if (kc < 224){
      stageAll(kc + 32, p ^ 1);
      #pragma unroll
      for (int mt = 0; mt < 2; ++mt){
        ah2[mt] = *(const short8*)(a0h + (size_t)mt * 4096 + kc + 32);
        al2[mt] = *(const short8*)(a0l + (size_t)mt * 4096 + kc + 32);
      }
    }
    {
      int r0 = (0 * 16 + l15) * 32 + (lq ^ swz) * 8;
      int r1 = (1 * 16 + l15) * 32 + (lq ^ swz) * 8;
      int r2 = (2 * 16 + l15) * 32 + (lq ^ swz) * 8;
      short8 bh0 = *(const short8*)(Bh + r0), bl0 = *(const short8*)(Bl + r0);
      short8 bh1 = *(const short8*)(Bh + r1), bl1 = *(const short8*)(Bl + r1);
      short8 bh2 = *(const short8*)(Bh + r2), bl2 = *(const short8*)(Bl + r2);
      acc[0][0] = MFMA16(al[0], bh0, acc[0][0]);
      acc[1][0] = MFMA16(al[1], bh0, acc[1][0]);
      acc[0][1] = MFMA16(al[0], bh1, acc[0][1]);
      acc[1][1] = MFMA16(al[1], bh1, acc[1][1]);
      acc[0][2] = MFMA16(al[0], bh2, acc[0][2]);
      acc[1][2] = MFMA16(al[1], bh2, acc[1][2]);
      acc[0][0] = MFMA16(ah[0], bl0, acc[0][0]);
      acc[1][0] = MFMA16(ah[1], bl0, acc[1][0]);
      acc[0][1] = MFMA16(ah[0], bl1, acc[0][1]);
      acc[1][1] = MFMA16(ah[1], bl1, acc[1][1]);
      acc[0][2] = MFMA16(ah[0], bl2, acc[0][2]);
      acc[1][2] = MFMA16(ah[1], bl2, acc[1][2]);
      acc[0][0] = MFMA16(ah[0], bh0, acc[0][0]);
      acc[1][0] = MFMA16(ah[1], bh0, acc[1][0]);
      acc[0][1] = MFMA16(ah[0], bh1, acc[0][1]);
      acc[1][1] = MFMA16(ah[1], bh1, acc[1][1]);
      acc[0][2] = MFMA16(ah[0], bh2, acc[0][2]);
      acc[1][2] = MFMA16(ah[1], bh2, acc[1][2]);
    }
    {
      int r3 = (3 * 16 + l15) * 32 + (lq ^ swz) * 8;
      int r4 = (4 * 16 + l15) * 32 + (lq ^ swz) * 8;
      short8 bh3 = *(const short8*)(Bh + r3), bl3 = *(const short8*)(Bl + r3);
      short8 bh4 = *(const short8*)(Bh + r4), bl4 = *(const short8*)(Bl + r4);
      acc[0][3] = MFMA16(al[0], bh3, acc[0][3]);
      acc[1][3] = MFMA16(al[1], bh3, acc[1][3]);
      acc[0][4] = MFMA16(al[0], bh4, acc[0][4]);
      acc[1][4] = MFMA16(al[1], bh4, acc[1][4]);
      acc[0][3] = MFMA16(ah[0], bl3, acc[0][3]);
      acc[1][3] = MFMA16(ah[1], bl3, acc[1][3]);
      acc[0][4] = MFMA16(ah[0], bl4, acc[0][4]);
      acc[1][4] = MFMA16(ah[1], bl4, acc[1][4]);
      acc[0][3] = MFMA16(ah[0], bh3, acc[0][3]);
      acc[1][3] = MFMA16(ah[1], bh3, acc[1][3]);
      acc[0][4] = MFMA16(ah[0], bh4, acc[0][4]);
      acc[1][4] = MFMA16(ah[1], bh4, acc[1][4]);
    }
    ah[0] = ah2[0]; ah[1] = ah2[1];
    al[0] = al2[0]; al[1] = al2[1];
    __syncthreads();
    p ^= 1;
  }

  // epilogue: per-wave 16x81 scratch overlaying the (dead) B buffers.
  float* redw = (float*)smem + wid * 1296;
  #pragma unroll
  for (int mt = 0; mt < 2; ++mt){
    #pragma unroll
    for (int nt = 0; nt < 5; ++nt)
      #pragma unroll
      for (int r = 0; r < 4; ++r)
        redw[(lq * 4 + r) * 81 + nt * 16 + l15] = acc[mt][nt][r];
    int row = lane >> 2;
    int q   = lane & 3;
    const float* basep = redw + row * 81 + q * 20;
    float vs[2]; int is[2];
    #pragma unroll
    for (int cc = 0; cc < 2; ++cc){
      float m = 0.5f * (1.0f + basep[cc * 10]); int mi = 0;
      #pragma unroll
      for (int p2 = 1; p2 < 10; ++p2){
        float v = 0.5f * (1.0f + basep[cc * 10 + p2]);
        if (v > m){ m = v; mi = p2; }
      }
      vs[cc] = m; is[cc] = mi;
    }
    int grow = rbw + mt * 16 + row;
    int gcol = bx * 8 + q * 2;
    *(float2*)(out + (size_t)grow * 1000 + gcol) = make_float2(vs[0], vs[1]);
    idxb[(size_t)grow * 1000 + gcol]     = (unsigned char)is[0];
    idxb[(size_t)grow * 1000 + gcol + 1] = (unsigned char)is[1];
  }
}

// ---------------- row pass (ILP softmax) + colsum tail (no fences) -------------
__global__ void k_row_pass(const float* __restrict__ out, const unsigned char* __restrict__ idxb,
                           const int* __restrict__ labels, int* __restrict__ cnt,
                           float* __restrict__ ce_sum, float* __restrict__ pos_usage,
                           float* __restrict__ neg_usage,
                           const unsigned short* __restrict__ Ph,
                           const unsigned short* __restrict__ Pl,
                           float* __restrict__ svec){
  int blk = blockIdx.x;
  if (blk >= 1024){
    int t = threadIdx.x;
    int r0 = (blk - 1024) * 100;
    float acc = 0.f;
    for (int rr = r0; rr < r0 + 100; ++rr)
      acc += bf2f(Ph[(size_t)rr * 256 + t]) + bf2f(Pl[(size_t)rr * 256 + t]);
    atomicAdd(&svec[t], acc);
    return;
  }
  int b = blk * 4 + (threadIdx.x >> 6);
  int lane = threadIdx.x & 63;
  const float* row = out + (size_t)b * 1000;
  float v[16];
  #pragma unroll
  for (int j = 0; j < 4; ++j){
    int f4 = j * 64 + lane;
    if (f4 < 250){
      float4 t = *(const float4*)(row + f4 * 4);
      v[j*4+0] = t.x; v[j*4+1] = t.y; v[j*4+2] = t.z; v[j*4+3] = t.w;
    } else {
      v[j*4+0] = v[j*4+1] = v[j*4+2] = v[j*4+3] = -INFINITY;
    }
  }
  float m = -INFINITY; int mi = 0x7fffffff;
  #pragma unroll
  for (int j = 0; j < 4; ++j)
    #pragma unroll
    for (int k = 0; k < 4; ++k){
      float x = v[j*4+k];
      if (x > m){ m = x; mi = (j * 64 + lane) * 4 + k; }
    }
  #pragma unroll
  for (int o = 32; o > 0; o >>= 1){
    float m2 = __shfl_xor(m, o);
    int   i2 = __shfl_xor(mi, o);
    if (m2 > m || (m2 == m && i2 < mi)){ m = m2; mi = i2; }
  }
  float s = 0.f;
  #pragma unroll
  for (int t = 0; t < 16; ++t) s += __expf(v[t] - m);
  s = waveReduceSum(s);
  if (lane == 0){
    int lab = labels[b];
    float true_score = row[lab];
    float per_ce = m + __logf(s) - true_score;
    bool mask = (true_score - m) > -0.1f;
    if (mask){ atomicAdd(cnt, 1); atomicAdd(ce_sum, per_ce); }
    int pi = idxb[(size_t)b * 1000 + lab];
    atomicAdd(&pos_usage[lab * P_ + pi], 1.f);
    if (mi != lab){
      int ni = idxb[(size_t)b * 1000 + mi];
      atomicAdd(&neg_usage[mi * P_ + ni], 1.f);
    }
  }
}

// ---------------- finalize loss ----------------
__global__ void k_finalize(const float* __restrict__ s, const int* __restrict__ cnt,
                           const float* __restrict__ ce_sum, float* __restrict__ loss_out){
  int t = threadIdx.x;
  float v = s[t];
  float ss = waveReduceSum(v * v);
  __shared__ float red[4];
  if ((t & 63) == 0) red[t >> 6] = ss;
  __syncthreads();
  if (t == 0){
    float tot = red[0] + red[1] + red[2] + red[3];
    float disp = -tot / 1.0e8f;
    int c = *cnt;
    float total = (c == 0) ? 0.f
                : (*ce_sum / (float)(c < 1 ? 1 : c) + 0.1f * disp);
    *loss_out = total;
  }
}

// ---------------- launcher ----------------
extern "C" void kernel_launch(void* const* d_in, const int* in_sizes, int n_in,
                              void* d_out, int out_size, void* d_ws, size_t ws_size,
                              hipStream_t stream){
  const float* hidden = (const float*)d_in[0];
  const int*   labels = (const int*)  d_in[1];
  const int*   eidx   = (const int*)  d_in[2];
  const float* nodef  = (const float*)d_in[3];
  const float* w1     = (const float*)d_in[4];
  const float* b1     = (const float*)d_in[5];
  const float* w2     = (const float*)d_in[6];
  const float* b2     = (const float*)d_in[7];

  float* out       = (float*)d_out;
  float* loss_out  = out + (size_t)B_ * C_;
  float* pos_usage = loss_out + 1;
  float* neg_usage = pos_usage + N_;

  const int* srcp = eidx;
  const int* dstp = eidx + E_;

  char* base = (char*)d_ws;
  size_t off = 0;
  auto alloc = [&](size_t bytes) -> char* {
    char* p = base + off;
    off = (off + bytes + 255) & ~(size_t)255;
    return p;
  };
  int*   cursor  = (int*)  alloc((size_t)N_ * 4);
  float* svec    = (float*)alloc(256 * 4);
  int*   cnt     = (int*)  alloc(4);
  float* ce_sum  = (float*)alloc(4);
  size_t zero_bytes = off;
  int*   csr_src   = (int*)  alloc((size_t)N_ * 64 * 4);
  float* XW        = (float*)alloc((size_t)N_ * 256 * 4);
  unsigned short* NFh = (unsigned short*)alloc((size_t)N_ * 256 * 2);
  unsigned short* NFl = (unsigned short*)alloc((size_t)N_ * 256 * 2);
  unsigned short* Xh  = (unsigned short*)alloc((size_t)N_ * 256 * 2);
  unsigned short* Xl  = (unsigned short*)alloc((size_t)N_ * 256 * 2);
  unsigned short* Ph  = (unsigned short*)alloc((size_t)N_ * 256 * 2);
  unsigned short* Pl  = (unsigned short*)alloc((size_t)N_ * 256 * 2);
  unsigned short* W1h = (unsigned short*)alloc(256 * 256 * 2);
  unsigned short* W1l = (unsigned short*)alloc(256 * 256 * 2);
  unsigned short* W2h = (unsigned short*)alloc(256 * 256 * 2);
  unsigned short* W2l = (unsigned short*)alloc(256 * 256 * 2);
  unsigned short* HNh = (unsigned short*)alloc((size_t)B_ * 256 * 2);
  unsigned short* HNl = (unsigned short*)alloc((size_t)B_ * 256 * 2);
  unsigned char* idxb = (unsigned char*)alloc((size_t)B_ * C_);

  hipMemsetAsync(base, 0, zero_bytes, stream);

  k_prep<<<15312, 256, 0, stream>>>(srcp, dstp, cursor, csr_src,
                                    w1, w2, W1h, W1l, W2h, W2l, loss_out,
                                    nodef, NFh, NFl, hidden, HNh, HNl);

  dim3 ggrid(157, 8);
  k_gemm_mfma<<<ggrid, 64, 0, stream>>>(NFh, NFl, W1h, W1l, XW);
  k_agg_split<<<N_ / 4, 256, 0, stream>>>(XW, cursor, csr_src, b1, Xh, Xl);
  k_gemm_mfma<<<ggrid, 64, 0, stream>>>(Xh, Xl, W2h, W2l, XW);
  k_agg_norm_split<<<N_ / 4, 256, 0, stream>>>(XW, cursor, csr_src, b2, Ph, Pl);

  k_sim_max<<<4096, 256, 0, stream>>>(HNh, HNl, Ph, Pl, out, idxb);

  k_row_pass<<<1124, 256, 0, stream>>>(out, idxb, labels, cnt, ce_sum,
                                       pos_usage, neg_usage, Ph, Pl, svec);
  k_finalize<<<1, 256, 0, stream>>>(svec, cnt, ce_sum, loss_out);
}